// Round 19
// baseline (224.357 us; speedup 1.0000x reference)
//
#include <hip/hip_runtime.h>
#include <hip/hip_fp16.h>
#include <cstdint>
#include <cstddef>
#include <type_traits>

#define N_NODES 30000
#define N_EDGES 480000
#define N_EDGES_SL (N_EDGES + N_NODES) // 510000
#define IN_CH 128
#define HEADS1 5
#define C1 64
#define D1 (HEADS1 * C1) // 320
#define OUT_CH 64
#define PE_CNT 100000
#define NEG_SLOPE 0.2f
#define BCAP 64 // bucket capacity; deg>BCAP goes to overflow list (cold path)
#define GEMM1_BLOCKS 469
#define BUCKET_BLOCKS 384 // R18: 128 -> 384. ONLY change this round: clean test of
                          // latency-vs-contention for the bucket atomic tail
                          // (R16/R17 tests were confounded by VGPR/compile changes).

typedef _Float16 f16x8 __attribute__((ext_vector_type(8)));
typedef _Float16 f16x2 __attribute__((ext_vector_type(2)));
typedef float fx4 __attribute__((ext_vector_type(4)));

#if defined(__has_builtin)
#if __has_builtin(__builtin_amdgcn_fdot2)
#define HAS_FDOT2 1
#endif
#endif

static __device__ __forceinline__ float leaky(float x) {
    return x > 0.f ? x : NEG_SLOPE * x;
}

// ---------------- barrier-free MFMA fp16 GEMM phase + fused attention scores ----------------
// Wave-slot per 16-row tile (30000 = 16*1875). No LDS, no barriers.
// mfma_f32_16x16x32_f16 layouts (HW-verified): A: lane holds A[m=lane&15][k=quad*8+j];
// B: lane holds B[k=quad*8+j][n=lane&15] (contiguous in Wt[n][k]); D: D[row=quad*4+reg][col=lane&15].
// Scores written HEAD-MAJOR: as_out[h*N_NODES + row].
template<int NH, typename AT>
static __device__ __forceinline__ void gemm_phase(const AT* __restrict__ A,
                                                  const __half* __restrict__ Wt,
                                                  __half* __restrict__ C, int K,
                                                  const float* __restrict__ att_src,
                                                  const float* __restrict__ att_dst,
                                                  float* __restrict__ as_out,
                                                  float* __restrict__ ad_out,
                                                  int slot, int nsl, int lane) {
    const int N = NH * 64;
    int q = lane >> 4, l16 = lane & 15;
    for (int tile = slot; tile < N_NODES / 16; tile += nsl) {
        int rowBase = tile * 16;
        int arow = rowBase + l16;
        fx4 zero4 = {0.f, 0.f, 0.f, 0.f};
        fx4 acc[NH][4];
#pragma unroll
        for (int h = 0; h < NH; ++h)
#pragma unroll
            for (int c = 0; c < 4; ++c) acc[h][c] = zero4;
        for (int kk = 0; kk < K; kk += 32) {
            f16x8 af;
            if constexpr (std::is_same<AT, float>::value) {
                const float4* s = (const float4*)(A + (size_t)arow * K + kk + q * 8);
                float4 v0 = s[0], v1 = s[1];
                af[0] = (_Float16)v0.x; af[1] = (_Float16)v0.y;
                af[2] = (_Float16)v0.z; af[3] = (_Float16)v0.w;
                af[4] = (_Float16)v1.x; af[5] = (_Float16)v1.y;
                af[6] = (_Float16)v1.z; af[7] = (_Float16)v1.w;
            } else {
                af = *(const f16x8*)((const __half*)A + (size_t)arow * K + kk + q * 8);
            }
#pragma unroll
            for (int h = 0; h < NH; ++h) {
#pragma unroll
                for (int c = 0; c < 4; ++c) {
                    int col = h * 64 + c * 16 + l16;
                    f16x8 bf = *(const f16x8*)(Wt + (size_t)col * K + kk + q * 8);
                    acc[h][c] = __builtin_amdgcn_mfma_f32_16x16x32_f16(af, bf, acc[h][c], 0, 0, 0);
                }
            }
        }
#pragma unroll
        for (int h = 0; h < NH; ++h) {
            float ps[4] = {0.f, 0.f, 0.f, 0.f};
            float pd[4] = {0.f, 0.f, 0.f, 0.f};
#pragma unroll
            for (int c = 0; c < 4; ++c) {
                int gcol = h * 64 + c * 16 + l16;
                float av = att_src[gcol];
                float dv = att_dst[gcol];
#pragma unroll
                for (int reg = 0; reg < 4; ++reg) {
                    int grow = rowBase + q * 4 + reg;
                    float val = acc[h][c][reg];
                    C[(size_t)grow * N + gcol] = __float2half(val);
                    ps[reg] += val * av;
                    pd[reg] += val * dv;
                }
            }
#pragma unroll
            for (int off = 1; off < 16; off <<= 1) {
#pragma unroll
                for (int reg = 0; reg < 4; ++reg) {
                    ps[reg] += __shfl_xor(ps[reg], off, 64);
                    pd[reg] += __shfl_xor(pd[reg], off, 64);
                }
            }
            if (l16 == 0) {
#pragma unroll
                for (int reg = 0; reg < 4; ++reg) {
                    int grow = rowBase + q * 4 + reg;
                    as_out[(size_t)h * N_NODES + grow] = ps[reg];
                    ad_out[(size_t)h * N_NODES + grow] = pd[reg];
                }
            }
        }
    }
}

// ================ K0: seed counters (self-loop pre-inserted) || weight transpose/cast ================
// cnt[i]=1 and esrc2[i*64]=i pre-insert the self-loop without atomics (30K fewer).
__global__ __launch_bounds__(256) void k_init(int* __restrict__ cnt,
                                              int* __restrict__ esrc2,
                                              const float* __restrict__ W1,
                                              __half* __restrict__ Wt1,
                                              const float* __restrict__ W2,
                                              __half* __restrict__ Wt2) {
    int t = blockIdx.x * 256 + threadIdx.x;
    int nthr = gridDim.x * 256;
    for (int i = t; i < N_NODES + 8; i += nthr) cnt[i] = (i < N_NODES) ? 1 : 0;
    for (int i = t; i < N_NODES; i += nthr) esrc2[i * BCAP] = i;
    const int T1 = IN_CH * D1, T2 = D1 * OUT_CH;
    for (int idx = t; idx < T1 + T2; idx += nthr) {
        if (idx < T1) {
            int k = idx / D1, n = idx - k * D1;
            Wt1[(size_t)n * IN_CH + k] = __float2half(W1[idx]);
        } else {
            int i2 = idx - T1;
            int k = i2 / OUT_CH, n = i2 - k * OUT_CH;
            Wt2[(size_t)n * D1 + k] = __float2half(W2[i2]);
        }
    }
}

// ================ K1: layer-1 GEMM || bucket insert (block-partitioned, R13 branch order) ================
// Disjoint data; both pure-parallel throughput work. GEMM branch FIRST —
// this ordering compiled to 116 VGPR (R15/R18); bucket-first compiled to 256 (R16).
// Bucket: rank r = atomicAdd(cnt[d]) IS the CSR position (slot 0 = self-loop,
// pre-seeded). Only the 480K real edges — no self-loop branch. Overflow -> list.
__global__ __launch_bounds__(256) void k_build_gemm1(const int* __restrict__ edge,
                                                     int* __restrict__ cnt,
                                                     int* __restrict__ esrc2,
                                                     int* __restrict__ ovf_cnt,
                                                     int* __restrict__ ovf,
                                                     const float* __restrict__ x,
                                                     const __half* __restrict__ Wt1,
                                                     __half* __restrict__ h1,
                                                     const float* __restrict__ att_src1,
                                                     const float* __restrict__ att_dst1,
                                                     float* __restrict__ as1,
                                                     float* __restrict__ ad1) {
    int lane = threadIdx.x & 63, wv = threadIdx.x >> 6;
    if (blockIdx.x < GEMM1_BLOCKS) {
        gemm_phase<HEADS1, float>(x, Wt1, h1, IN_CH, att_src1, att_dst1, as1, ad1,
                                  blockIdx.x * 4 + wv, GEMM1_BLOCKS * 4, lane);
    } else {
        int t = (blockIdx.x - GEMM1_BLOCKS) * 256 + threadIdx.x;
        int nthr = BUCKET_BLOCKS * 256;
        for (int e = t; e < N_EDGES; e += nthr) {
            int s = edge[e];
            int d = edge[N_EDGES + e];
            int r = atomicAdd(&cnt[d], 1);
            if (r < BCAP) {
                esrc2[d * BCAP + r] = s;
            } else {
                int oi = atomicAdd(ovf_cnt, 1);
                ovf[2 * oi] = d;
                ovf[2 * oi + 1] = s;
            }
        }
    }
}

// ================ fused softmax + weighted aggregate (bucket CSR) — R13-proven ================
// wave per (node,head), HEAD-MAJOR grid; scores HEAD-MAJOR [h][N].
// No max-subtract (inputs bounded; exp/sum identical). Weights pre-normalized
// (w' = exp*r) packed half2 in per-wave LDS (computed once per edge). Gather:
// lane = es*8+cg, FOUR independent 16B loads in flight, __hfma2 fp16
// accumulate. Cross-es reduce: LDS pad-9 transpose (measured > dependent-
// shuffle tree, R12). deg>BCAP: cold lane=channel path + overflow list.
template<int NH, bool RELU>
__global__ __launch_bounds__(256) void k_attn_agg(const int* __restrict__ cnt,
                                                  const int* __restrict__ esrc2,
                                                  const int* __restrict__ ovf_cnt,
                                                  const int* __restrict__ ovf,
                                                  const __half* __restrict__ hf,   // [N][NH*64]
                                                  const float* __restrict__ a_src, // [NH][N]
                                                  const float* __restrict__ a_dst, // [NH][N]
                                                  const float* __restrict__ bias,  // [NH*64]
                                                  __half* __restrict__ zout) {     // [N][NH*64]
    __shared__ unsigned wpk[4][64];
    __shared__ int jbuf[4][64];
    __shared__ float red[4][584];
    int wid = (blockIdx.x * 256 + threadIdx.x) >> 6;
    int lane = threadIdx.x & 63;
    int wv = threadIdx.x >> 6;
    if (wid >= N_NODES * NH) return;
    int h = wid / N_NODES;
    int node = wid - h * N_NODES;
    int deg = cnt[node];
    const float* asrc_h = a_src + (size_t)h * N_NODES;
    float adst = a_dst[(size_t)h * N_NODES + node];
    const int RS = NH * 64;
    if (deg <= BCAP) {
        int es = lane >> 3, cg = lane & 7;
        const __half* hbase = hf + h * 64 + cg * 8;
        int j = 0;
        float ex = 0.f;
        if (lane < deg) {
            j = esrc2[node * BCAP + lane];
            ex = __expf(leaky(asrc_h[j] + adst));
        }
        float s = ex;
#pragma unroll
        for (int off = 1; off < 64; off <<= 1)
            s += __shfl_xor(s, off, 64);
        float r = 1.f / (s + 1e-16f);
        __half2 wn = __float2half2_rn(ex * r);
        wpk[wv][lane] = *(unsigned*)&wn;
        jbuf[wv][lane] = j;
        __half2 acch[4] = {__half2{0, 0}, __half2{0, 0}, __half2{0, 0}, __half2{0, 0}};
        for (int k0 = 0; k0 < deg; k0 += 32) {
            int kA = k0 + es, kB = k0 + 8 + es, kC = k0 + 16 + es, kD = k0 + 24 + es;
            bool oA = kA < deg, oB = kB < deg, oC = kC < deg, oD = kD < deg;
            unsigned uA = oA ? wpk[wv][kA] : 0u;
            unsigned uB = oB ? wpk[wv][kB] : 0u;
            unsigned uC = oC ? wpk[wv][kC] : 0u;
            unsigned uD = oD ? wpk[wv][kD] : 0u;
            int jA = jbuf[wv][oA ? kA : 0];
            int jB = jbuf[wv][oB ? kB : 0];
            int jC = jbuf[wv][oC ? kC : 0];
            int jD = jbuf[wv][oD ? kD : 0];
            float4 vA = *(const float4*)(hbase + (size_t)jA * RS);
            float4 vB = *(const float4*)(hbase + (size_t)jB * RS);
            float4 vC = *(const float4*)(hbase + (size_t)jC * RS);
            float4 vD = *(const float4*)(hbase + (size_t)jD * RS);
            __half2 hwA = *(__half2*)&uA, hwB = *(__half2*)&uB;
            __half2 hwC = *(__half2*)&uC, hwD = *(__half2*)&uD;
            const __half2* pA = (const __half2*)&vA;
            const __half2* pB = (const __half2*)&vB;
            const __half2* pC = (const __half2*)&vC;
            const __half2* pD = (const __half2*)&vD;
#pragma unroll
            for (int i = 0; i < 4; ++i) {
                acch[i] = __hfma2(pA[i], hwA, acch[i]);
                acch[i] = __hfma2(pB[i], hwB, acch[i]);
                acch[i] = __hfma2(pC[i], hwC, acch[i]);
                acch[i] = __hfma2(pD[i], hwD, acch[i]);
            }
        }
        // fp32 cross-es reduce via LDS pad-9 transpose (2-way conflicts = free)
#pragma unroll
        for (int i = 0; i < 4; ++i) {
            float2 f = __half22float2(acch[i]);
            red[wv][(cg * 8 + 2 * i) * 9 + es] = f.x;
            red[wv][(cg * 8 + 2 * i + 1) * 9 + es] = f.y;
        }
        float tot = 0.f;
#pragma unroll
        for (int e2 = 0; e2 < 8; ++e2)
            tot += red[wv][lane * 9 + e2];
        float o = tot + bias[h * 64 + lane];
        if (RELU) o = fmaxf(o, 0.f);
        zout[(size_t)node * RS + h * 64 + lane] = __float2half(o);
    } else {
        // cold path: deg > BCAP. lane = channel; bucket (64 full) + overflow scan.
        int ovn = *ovf_cnt;
        float s = __expf(leaky(asrc_h[esrc2[node * BCAP + lane]] + adst));
#pragma unroll
        for (int off = 1; off < 64; off <<= 1)
            s += __shfl_xor(s, off, 64);
        float s2 = 0.f;
        for (int k = lane; k < ovn; k += 64)
            if (ovf[2 * k] == node)
                s2 += __expf(leaky(asrc_h[ovf[2 * k + 1]] + adst));
#pragma unroll
        for (int off = 1; off < 64; off <<= 1)
            s2 += __shfl_xor(s2, off, 64);
        float r = 1.f / (s + s2 + 1e-16f);
        float a = 0.f;
        for (int k = 0; k < BCAP; ++k) {
            int j = esrc2[node * BCAP + k];
            float w = __expf(leaky(asrc_h[j] + adst));
            a += w * __half2float(hf[(size_t)j * RS + h * 64 + lane]);
        }
        for (int k = 0; k < ovn; ++k) {
            if (ovf[2 * k] == node) {
                int j = ovf[2 * k + 1];
                float w = __expf(leaky(asrc_h[j] + adst));
                a += w * __half2float(hf[(size_t)j * RS + h * 64 + lane]);
            }
        }
        float o = a * r + bias[h * 64 + lane];
        if (RELU) o = fmaxf(o, 0.f);
        zout[(size_t)node * RS + h * 64 + lane] = __float2half(o);
    }
}

// ================ layer-2 GEMM (slot-strided, 256-thr blocks) ================
__global__ __launch_bounds__(256) void k_gemm2(const __half* __restrict__ z1,
                                               const __half* __restrict__ Wt2,
                                               __half* __restrict__ h2,
                                               const float* __restrict__ att_src2,
                                               const float* __restrict__ att_dst2,
                                               float* __restrict__ as2,
                                               float* __restrict__ ad2) {
    int lane = threadIdx.x & 63, wv = threadIdx.x >> 6;
    gemm_phase<1, __half>(z1, Wt2, h2, D1, att_src2, att_dst2, as2, ad2,
                          blockIdx.x * 4 + wv, gridDim.x * 4, lane);
}

// ================ decode: 8 lanes per edge, 16B fp16 loads, fdot2 ================
__global__ __launch_bounds__(256) void k_decode(const int* __restrict__ pos,
                                                const int* __restrict__ neg,
                                                const __half* __restrict__ z2,
                                                float* __restrict__ out) {
    int t = blockIdx.x * 256 + threadIdx.x;
    int e = t >> 3;
    int lc = t & 7;
    if (e >= 2 * PE_CNT) return;
    int a, b;
    if (e < PE_CNT) { a = pos[e]; b = pos[PE_CNT + e]; }
    else { int k = e - PE_CNT; a = neg[k]; b = neg[PE_CNT + k]; }
    union U { float4 f; f16x2 h[4]; __half2 hh[4]; } ua, ub;
    ua.f = *(const float4*)(z2 + (size_t)a * OUT_CH + lc * 8);
    ub.f = *(const float4*)(z2 + (size_t)b * OUT_CH + lc * 8);
    float v = 0.f;
#pragma unroll
    for (int i = 0; i < 4; ++i) {
#ifdef HAS_FDOT2
        v = __builtin_amdgcn_fdot2(ua.h[i], ub.h[i], v, false);
#else
        float2 fa = __half22float2(ua.hh[i]);
        float2 fb = __half22float2(ub.hh[i]);
        v += fa.x * fb.x + fa.y * fb.y;
#endif
    }
#pragma unroll
    for (int off = 1; off < 8; off <<= 1)
        v += __shfl_xor(v, off, 64);
    if (lc == 0) out[e] = v;
}

extern "C" void kernel_launch(void* const* d_in, const int* in_sizes, int n_in,
                              void* d_out, int out_size, void* d_ws, size_t ws_size,
                              hipStream_t stream) {
    const float* x        = (const float*)d_in[0];
    const int* edge_index = (const int*)d_in[1];
    const int* pos_ei     = (const int*)d_in[2];
    const int* neg_ei     = (const int*)d_in[3];
    const float* W1       = (const float*)d_in[4];
    const float* att_src1 = (const float*)d_in[5];
    const float* att_dst1 = (const float*)d_in[6];
    const float* b1       = (const float*)d_in[7];
    const float* W2       = (const float*)d_in[8];
    const float* att_src2 = (const float*)d_in[9];
    const float* att_dst2 = (const float*)d_in[10];
    const float* b2       = (const float*)d_in[11];
    float* out            = (float*)d_out;

    char* ws = (char*)d_ws;
    size_t off = 0;
    auto alloc = [&](size_t bytes) -> void* {
        void* p = ws + off;
        off = (off + bytes + 255) & ~(size_t)255;
        return p;
    };
    int* cnt     = (int*)alloc(sizeof(int) * (N_NODES + 8)); // cnt + ovf_cnt (seeded by k_init)
    int* ovfc    = cnt + N_NODES;
    int* esrc2   = (int*)alloc(sizeof(int) * (size_t)N_NODES * BCAP);
    int* ovf     = (int*)alloc(sizeof(int) * (size_t)2 * N_EDGES_SL);
    __half* h1   = (__half*)alloc(sizeof(__half) * (size_t)N_NODES * D1);
    __half* z1   = (__half*)alloc(sizeof(__half) * (size_t)N_NODES * D1);
    __half* h2   = (__half*)alloc(sizeof(__half) * (size_t)N_NODES * OUT_CH);
    __half* z2   = (__half*)alloc(sizeof(__half) * (size_t)N_NODES * OUT_CH);
    __half* Wt1  = (__half*)alloc(sizeof(__half) * (size_t)D1 * IN_CH);
    __half* Wt2  = (__half*)alloc(sizeof(__half) * (size_t)OUT_CH * D1);
    float* as1   = (float*)alloc(sizeof(float) * (size_t)N_NODES * HEADS1); // [h][N]
    float* ad1   = (float*)alloc(sizeof(float) * (size_t)N_NODES * HEADS1); // [h][N]
    float* as2   = (float*)alloc(sizeof(float) * (size_t)N_NODES);
    float* ad2   = (float*)alloc(sizeof(float) * (size_t)N_NODES);

    // K0: seed counters + self-loops || weight prep
    k_init<<<240, 256, 0, stream>>>(cnt, esrc2, W1, Wt1, W2, Wt2);
    // K1: layer-1 MFMA GEMM + scores || bucket CSR build (one pass, block-split)
    k_build_gemm1<<<GEMM1_BLOCKS + BUCKET_BLOCKS, 256, 0, stream>>>(
        edge_index, cnt, esrc2, ovfc, ovf, x, Wt1, h1, att_src1, att_dst1, as1, ad1);
    // K2: layer-1 softmax-aggregate (+relu)
    k_attn_agg<HEADS1, true><<<(N_NODES * HEADS1 + 3) / 4, 256, 0, stream>>>(
        cnt, esrc2, ovfc, ovf, h1, as1, ad1, b1, z1);
    // K3: layer-2 GEMM + scores
    k_gemm2<<<469, 256, 0, stream>>>(z1, Wt2, h2, att_src2, att_dst2, as2, ad2);
    // K4: layer-2 softmax-aggregate
    k_attn_agg<1, false><<<(N_NODES + 3) / 4, 256, 0, stream>>>(
        cnt, esrc2, ovfc, ovf, h2, as2, ad2, b2, z2);
    // K5: decode
    k_decode<<<(2 * PE_CNT * 8 + 255) / 256, 256, 0, stream>>>(pos_ei, neg_ei, z2, out);

    (void)in_sizes; (void)n_in; (void)out_size; (void)ws_size;
}

// Round 20
// 211.890 us; speedup vs baseline: 1.0588x; 1.0588x over previous
//
#include <hip/hip_runtime.h>
#include <hip/hip_fp16.h>
#include <cstdint>
#include <cstddef>
#include <type_traits>

#define N_NODES 30000
#define N_EDGES 480000
#define N_EDGES_SL (N_EDGES + N_NODES) // 510000
#define IN_CH 128
#define HEADS1 5
#define C1 64
#define D1 (HEADS1 * C1) // 320
#define OUT_CH 64
#define PE_CNT 100000
#define NEG_SLOPE 0.2f
#define BCAP 64 // bucket capacity; deg>BCAP goes to overflow list (cold path)
#define GEMM1_BLOCKS 469
#define BUCKET_BLOCKS 128 // R19 verdict: bucket pass is CONTENTION-bound, not
                          // latency-bound — 384 blocks regressed (224us vs 213).
                          // 128 is the measured optimum (R13/R18 = 212.7us).

typedef _Float16 f16x8 __attribute__((ext_vector_type(8)));
typedef _Float16 f16x2 __attribute__((ext_vector_type(2)));
typedef float fx4 __attribute__((ext_vector_type(4)));

#if defined(__has_builtin)
#if __has_builtin(__builtin_amdgcn_fdot2)
#define HAS_FDOT2 1
#endif
#endif

static __device__ __forceinline__ float leaky(float x) {
    return x > 0.f ? x : NEG_SLOPE * x;
}

// ---------------- barrier-free MFMA fp16 GEMM phase + fused attention scores ----------------
// Wave-slot per 16-row tile (30000 = 16*1875). No LDS, no barriers.
// mfma_f32_16x16x32_f16 layouts (HW-verified): A: lane holds A[m=lane&15][k=quad*8+j];
// B: lane holds B[k=quad*8+j][n=lane&15] (contiguous in Wt[n][k]); D: D[row=quad*4+reg][col=lane&15].
// Scores written HEAD-MAJOR: as_out[h*N_NODES + row].
template<int NH, typename AT>
static __device__ __forceinline__ void gemm_phase(const AT* __restrict__ A,
                                                  const __half* __restrict__ Wt,
                                                  __half* __restrict__ C, int K,
                                                  const float* __restrict__ att_src,
                                                  const float* __restrict__ att_dst,
                                                  float* __restrict__ as_out,
                                                  float* __restrict__ ad_out,
                                                  int slot, int nsl, int lane) {
    const int N = NH * 64;
    int q = lane >> 4, l16 = lane & 15;
    for (int tile = slot; tile < N_NODES / 16; tile += nsl) {
        int rowBase = tile * 16;
        int arow = rowBase + l16;
        fx4 zero4 = {0.f, 0.f, 0.f, 0.f};
        fx4 acc[NH][4];
#pragma unroll
        for (int h = 0; h < NH; ++h)
#pragma unroll
            for (int c = 0; c < 4; ++c) acc[h][c] = zero4;
        for (int kk = 0; kk < K; kk += 32) {
            f16x8 af;
            if constexpr (std::is_same<AT, float>::value) {
                const float4* s = (const float4*)(A + (size_t)arow * K + kk + q * 8);
                float4 v0 = s[0], v1 = s[1];
                af[0] = (_Float16)v0.x; af[1] = (_Float16)v0.y;
                af[2] = (_Float16)v0.z; af[3] = (_Float16)v0.w;
                af[4] = (_Float16)v1.x; af[5] = (_Float16)v1.y;
                af[6] = (_Float16)v1.z; af[7] = (_Float16)v1.w;
            } else {
                af = *(const f16x8*)((const __half*)A + (size_t)arow * K + kk + q * 8);
            }
#pragma unroll
            for (int h = 0; h < NH; ++h) {
#pragma unroll
                for (int c = 0; c < 4; ++c) {
                    int col = h * 64 + c * 16 + l16;
                    f16x8 bf = *(const f16x8*)(Wt + (size_t)col * K + kk + q * 8);
                    acc[h][c] = __builtin_amdgcn_mfma_f32_16x16x32_f16(af, bf, acc[h][c], 0, 0, 0);
                }
            }
        }
#pragma unroll
        for (int h = 0; h < NH; ++h) {
            float ps[4] = {0.f, 0.f, 0.f, 0.f};
            float pd[4] = {0.f, 0.f, 0.f, 0.f};
#pragma unroll
            for (int c = 0; c < 4; ++c) {
                int gcol = h * 64 + c * 16 + l16;
                float av = att_src[gcol];
                float dv = att_dst[gcol];
#pragma unroll
                for (int reg = 0; reg < 4; ++reg) {
                    int grow = rowBase + q * 4 + reg;
                    float val = acc[h][c][reg];
                    C[(size_t)grow * N + gcol] = __float2half(val);
                    ps[reg] += val * av;
                    pd[reg] += val * dv;
                }
            }
#pragma unroll
            for (int off = 1; off < 16; off <<= 1) {
#pragma unroll
                for (int reg = 0; reg < 4; ++reg) {
                    ps[reg] += __shfl_xor(ps[reg], off, 64);
                    pd[reg] += __shfl_xor(pd[reg], off, 64);
                }
            }
            if (l16 == 0) {
#pragma unroll
                for (int reg = 0; reg < 4; ++reg) {
                    int grow = rowBase + q * 4 + reg;
                    as_out[(size_t)h * N_NODES + grow] = ps[reg];
                    ad_out[(size_t)h * N_NODES + grow] = pd[reg];
                }
            }
        }
    }
}

// ================ K0: seed counters (self-loop pre-inserted) || weight transpose/cast ================
// cnt[i]=1 and esrc2[i*64]=i pre-insert the self-loop without atomics (30K fewer).
__global__ __launch_bounds__(256) void k_init(int* __restrict__ cnt,
                                              int* __restrict__ esrc2,
                                              const float* __restrict__ W1,
                                              __half* __restrict__ Wt1,
                                              const float* __restrict__ W2,
                                              __half* __restrict__ Wt2) {
    int t = blockIdx.x * 256 + threadIdx.x;
    int nthr = gridDim.x * 256;
    for (int i = t; i < N_NODES + 8; i += nthr) cnt[i] = (i < N_NODES) ? 1 : 0;
    for (int i = t; i < N_NODES; i += nthr) esrc2[i * BCAP] = i;
    const int T1 = IN_CH * D1, T2 = D1 * OUT_CH;
    for (int idx = t; idx < T1 + T2; idx += nthr) {
        if (idx < T1) {
            int k = idx / D1, n = idx - k * D1;
            Wt1[(size_t)n * IN_CH + k] = __float2half(W1[idx]);
        } else {
            int i2 = idx - T1;
            int k = i2 / OUT_CH, n = i2 - k * OUT_CH;
            Wt2[(size_t)n * D1 + k] = __float2half(W2[i2]);
        }
    }
}

// ================ K1: layer-1 GEMM || bucket insert (block-partitioned, R13 branch order) ================
// Disjoint data; both pure-parallel throughput work. GEMM branch FIRST —
// this ordering compiled to 116 VGPR (R15/R18); bucket-first compiled to 256 (R16).
// Bucket: rank r = atomicAdd(cnt[d]) IS the CSR position (slot 0 = self-loop,
// pre-seeded). Only the 480K real edges — no self-loop branch. Overflow -> list.
__global__ __launch_bounds__(256) void k_build_gemm1(const int* __restrict__ edge,
                                                     int* __restrict__ cnt,
                                                     int* __restrict__ esrc2,
                                                     int* __restrict__ ovf_cnt,
                                                     int* __restrict__ ovf,
                                                     const float* __restrict__ x,
                                                     const __half* __restrict__ Wt1,
                                                     __half* __restrict__ h1,
                                                     const float* __restrict__ att_src1,
                                                     const float* __restrict__ att_dst1,
                                                     float* __restrict__ as1,
                                                     float* __restrict__ ad1) {
    int lane = threadIdx.x & 63, wv = threadIdx.x >> 6;
    if (blockIdx.x < GEMM1_BLOCKS) {
        gemm_phase<HEADS1, float>(x, Wt1, h1, IN_CH, att_src1, att_dst1, as1, ad1,
                                  blockIdx.x * 4 + wv, GEMM1_BLOCKS * 4, lane);
    } else {
        int t = (blockIdx.x - GEMM1_BLOCKS) * 256 + threadIdx.x;
        int nthr = BUCKET_BLOCKS * 256;
        for (int e = t; e < N_EDGES; e += nthr) {
            int s = edge[e];
            int d = edge[N_EDGES + e];
            int r = atomicAdd(&cnt[d], 1);
            if (r < BCAP) {
                esrc2[d * BCAP + r] = s;
            } else {
                int oi = atomicAdd(ovf_cnt, 1);
                ovf[2 * oi] = d;
                ovf[2 * oi + 1] = s;
            }
        }
    }
}

// ================ fused softmax + weighted aggregate (bucket CSR) — R13-proven ================
// wave per (node,head), HEAD-MAJOR grid; scores HEAD-MAJOR [h][N].
// No max-subtract (inputs bounded; exp/sum identical). Weights pre-normalized
// (w' = exp*r) packed half2 in per-wave LDS (computed once per edge). Gather:
// lane = es*8+cg, FOUR independent 16B loads in flight, __hfma2 fp16
// accumulate. Cross-es reduce: LDS pad-9 transpose (measured > dependent-
// shuffle tree, R12). deg>BCAP: cold lane=channel path + overflow list.
template<int NH, bool RELU>
__global__ __launch_bounds__(256) void k_attn_agg(const int* __restrict__ cnt,
                                                  const int* __restrict__ esrc2,
                                                  const int* __restrict__ ovf_cnt,
                                                  const int* __restrict__ ovf,
                                                  const __half* __restrict__ hf,   // [N][NH*64]
                                                  const float* __restrict__ a_src, // [NH][N]
                                                  const float* __restrict__ a_dst, // [NH][N]
                                                  const float* __restrict__ bias,  // [NH*64]
                                                  __half* __restrict__ zout) {     // [N][NH*64]
    __shared__ unsigned wpk[4][64];
    __shared__ int jbuf[4][64];
    __shared__ float red[4][584];
    int wid = (blockIdx.x * 256 + threadIdx.x) >> 6;
    int lane = threadIdx.x & 63;
    int wv = threadIdx.x >> 6;
    if (wid >= N_NODES * NH) return;
    int h = wid / N_NODES;
    int node = wid - h * N_NODES;
    int deg = cnt[node];
    const float* asrc_h = a_src + (size_t)h * N_NODES;
    float adst = a_dst[(size_t)h * N_NODES + node];
    const int RS = NH * 64;
    if (deg <= BCAP) {
        int es = lane >> 3, cg = lane & 7;
        const __half* hbase = hf + h * 64 + cg * 8;
        int j = 0;
        float ex = 0.f;
        if (lane < deg) {
            j = esrc2[node * BCAP + lane];
            ex = __expf(leaky(asrc_h[j] + adst));
        }
        float s = ex;
#pragma unroll
        for (int off = 1; off < 64; off <<= 1)
            s += __shfl_xor(s, off, 64);
        float r = 1.f / (s + 1e-16f);
        __half2 wn = __float2half2_rn(ex * r);
        wpk[wv][lane] = *(unsigned*)&wn;
        jbuf[wv][lane] = j;
        __half2 acch[4] = {__half2{0, 0}, __half2{0, 0}, __half2{0, 0}, __half2{0, 0}};
        for (int k0 = 0; k0 < deg; k0 += 32) {
            int kA = k0 + es, kB = k0 + 8 + es, kC = k0 + 16 + es, kD = k0 + 24 + es;
            bool oA = kA < deg, oB = kB < deg, oC = kC < deg, oD = kD < deg;
            unsigned uA = oA ? wpk[wv][kA] : 0u;
            unsigned uB = oB ? wpk[wv][kB] : 0u;
            unsigned uC = oC ? wpk[wv][kC] : 0u;
            unsigned uD = oD ? wpk[wv][kD] : 0u;
            int jA = jbuf[wv][oA ? kA : 0];
            int jB = jbuf[wv][oB ? kB : 0];
            int jC = jbuf[wv][oC ? kC : 0];
            int jD = jbuf[wv][oD ? kD : 0];
            float4 vA = *(const float4*)(hbase + (size_t)jA * RS);
            float4 vB = *(const float4*)(hbase + (size_t)jB * RS);
            float4 vC = *(const float4*)(hbase + (size_t)jC * RS);
            float4 vD = *(const float4*)(hbase + (size_t)jD * RS);
            __half2 hwA = *(__half2*)&uA, hwB = *(__half2*)&uB;
            __half2 hwC = *(__half2*)&uC, hwD = *(__half2*)&uD;
            const __half2* pA = (const __half2*)&vA;
            const __half2* pB = (const __half2*)&vB;
            const __half2* pC = (const __half2*)&vC;
            const __half2* pD = (const __half2*)&vD;
#pragma unroll
            for (int i = 0; i < 4; ++i) {
                acch[i] = __hfma2(pA[i], hwA, acch[i]);
                acch[i] = __hfma2(pB[i], hwB, acch[i]);
                acch[i] = __hfma2(pC[i], hwC, acch[i]);
                acch[i] = __hfma2(pD[i], hwD, acch[i]);
            }
        }
        // fp32 cross-es reduce via LDS pad-9 transpose (2-way conflicts = free)
#pragma unroll
        for (int i = 0; i < 4; ++i) {
            float2 f = __half22float2(acch[i]);
            red[wv][(cg * 8 + 2 * i) * 9 + es] = f.x;
            red[wv][(cg * 8 + 2 * i + 1) * 9 + es] = f.y;
        }
        float tot = 0.f;
#pragma unroll
        for (int e2 = 0; e2 < 8; ++e2)
            tot += red[wv][lane * 9 + e2];
        float o = tot + bias[h * 64 + lane];
        if (RELU) o = fmaxf(o, 0.f);
        zout[(size_t)node * RS + h * 64 + lane] = __float2half(o);
    } else {
        // cold path: deg > BCAP. lane = channel; bucket (64 full) + overflow scan.
        int ovn = *ovf_cnt;
        float s = __expf(leaky(asrc_h[esrc2[node * BCAP + lane]] + adst));
#pragma unroll
        for (int off = 1; off < 64; off <<= 1)
            s += __shfl_xor(s, off, 64);
        float s2 = 0.f;
        for (int k = lane; k < ovn; k += 64)
            if (ovf[2 * k] == node)
                s2 += __expf(leaky(asrc_h[ovf[2 * k + 1]] + adst));
#pragma unroll
        for (int off = 1; off < 64; off <<= 1)
            s2 += __shfl_xor(s2, off, 64);
        float r = 1.f / (s + s2 + 1e-16f);
        float a = 0.f;
        for (int k = 0; k < BCAP; ++k) {
            int j = esrc2[node * BCAP + k];
            float w = __expf(leaky(asrc_h[j] + adst));
            a += w * __half2float(hf[(size_t)j * RS + h * 64 + lane]);
        }
        for (int k = 0; k < ovn; ++k) {
            if (ovf[2 * k] == node) {
                int j = ovf[2 * k + 1];
                float w = __expf(leaky(asrc_h[j] + adst));
                a += w * __half2float(hf[(size_t)j * RS + h * 64 + lane]);
            }
        }
        float o = a * r + bias[h * 64 + lane];
        if (RELU) o = fmaxf(o, 0.f);
        zout[(size_t)node * RS + h * 64 + lane] = __float2half(o);
    }
}

// ================ layer-2 GEMM (slot-strided, 256-thr blocks) ================
__global__ __launch_bounds__(256) void k_gemm2(const __half* __restrict__ z1,
                                               const __half* __restrict__ Wt2,
                                               __half* __restrict__ h2,
                                               const float* __restrict__ att_src2,
                                               const float* __restrict__ att_dst2,
                                               float* __restrict__ as2,
                                               float* __restrict__ ad2) {
    int lane = threadIdx.x & 63, wv = threadIdx.x >> 6;
    gemm_phase<1, __half>(z1, Wt2, h2, D1, att_src2, att_dst2, as2, ad2,
                          blockIdx.x * 4 + wv, gridDim.x * 4, lane);
}

// ================ decode: 8 lanes per edge, 16B fp16 loads, fdot2 ================
__global__ __launch_bounds__(256) void k_decode(const int* __restrict__ pos,
                                                const int* __restrict__ neg,
                                                const __half* __restrict__ z2,
                                                float* __restrict__ out) {
    int t = blockIdx.x * 256 + threadIdx.x;
    int e = t >> 3;
    int lc = t & 7;
    if (e >= 2 * PE_CNT) return;
    int a, b;
    if (e < PE_CNT) { a = pos[e]; b = pos[PE_CNT + e]; }
    else { int k = e - PE_CNT; a = neg[k]; b = neg[PE_CNT + k]; }
    union U { float4 f; f16x2 h[4]; __half2 hh[4]; } ua, ub;
    ua.f = *(const float4*)(z2 + (size_t)a * OUT_CH + lc * 8);
    ub.f = *(const float4*)(z2 + (size_t)b * OUT_CH + lc * 8);
    float v = 0.f;
#pragma unroll
    for (int i = 0; i < 4; ++i) {
#ifdef HAS_FDOT2
        v = __builtin_amdgcn_fdot2(ua.h[i], ub.h[i], v, false);
#else
        float2 fa = __half22float2(ua.hh[i]);
        float2 fb = __half22float2(ub.hh[i]);
        v += fa.x * fb.x + fa.y * fb.y;
#endif
    }
#pragma unroll
    for (int off = 1; off < 8; off <<= 1)
        v += __shfl_xor(v, off, 64);
    if (lc == 0) out[e] = v;
}

extern "C" void kernel_launch(void* const* d_in, const int* in_sizes, int n_in,
                              void* d_out, int out_size, void* d_ws, size_t ws_size,
                              hipStream_t stream) {
    const float* x        = (const float*)d_in[0];
    const int* edge_index = (const int*)d_in[1];
    const int* pos_ei     = (const int*)d_in[2];
    const int* neg_ei     = (const int*)d_in[3];
    const float* W1       = (const float*)d_in[4];
    const float* att_src1 = (const float*)d_in[5];
    const float* att_dst1 = (const float*)d_in[6];
    const float* b1       = (const float*)d_in[7];
    const float* W2       = (const float*)d_in[8];
    const float* att_src2 = (const float*)d_in[9];
    const float* att_dst2 = (const float*)d_in[10];
    const float* b2       = (const float*)d_in[11];
    float* out            = (float*)d_out;

    char* ws = (char*)d_ws;
    size_t off = 0;
    auto alloc = [&](size_t bytes) -> void* {
        void* p = ws + off;
        off = (off + bytes + 255) & ~(size_t)255;
        return p;
    };
    int* cnt     = (int*)alloc(sizeof(int) * (N_NODES + 8)); // cnt + ovf_cnt (seeded by k_init)
    int* ovfc    = cnt + N_NODES;
    int* esrc2   = (int*)alloc(sizeof(int) * (size_t)N_NODES * BCAP);
    int* ovf     = (int*)alloc(sizeof(int) * (size_t)2 * N_EDGES_SL);
    __half* h1   = (__half*)alloc(sizeof(__half) * (size_t)N_NODES * D1);
    __half* z1   = (__half*)alloc(sizeof(__half) * (size_t)N_NODES * D1);
    __half* h2   = (__half*)alloc(sizeof(__half) * (size_t)N_NODES * OUT_CH);
    __half* z2   = (__half*)alloc(sizeof(__half) * (size_t)N_NODES * OUT_CH);
    __half* Wt1  = (__half*)alloc(sizeof(__half) * (size_t)D1 * IN_CH);
    __half* Wt2  = (__half*)alloc(sizeof(__half) * (size_t)OUT_CH * D1);
    float* as1   = (float*)alloc(sizeof(float) * (size_t)N_NODES * HEADS1); // [h][N]
    float* ad1   = (float*)alloc(sizeof(float) * (size_t)N_NODES * HEADS1); // [h][N]
    float* as2   = (float*)alloc(sizeof(float) * (size_t)N_NODES);
    float* ad2   = (float*)alloc(sizeof(float) * (size_t)N_NODES);

    // K0: seed counters + self-loops || weight prep
    k_init<<<240, 256, 0, stream>>>(cnt, esrc2, W1, Wt1, W2, Wt2);
    // K1: layer-1 MFMA GEMM + scores || bucket CSR build (one pass, block-split)
    k_build_gemm1<<<GEMM1_BLOCKS + BUCKET_BLOCKS, 256, 0, stream>>>(
        edge_index, cnt, esrc2, ovfc, ovf, x, Wt1, h1, att_src1, att_dst1, as1, ad1);
    // K2: layer-1 softmax-aggregate (+relu)
    k_attn_agg<HEADS1, true><<<(N_NODES * HEADS1 + 3) / 4, 256, 0, stream>>>(
        cnt, esrc2, ovfc, ovf, h1, as1, ad1, b1, z1);
    // K3: layer-2 GEMM + scores
    k_gemm2<<<469, 256, 0, stream>>>(z1, Wt2, h2, att_src2, att_dst2, as2, ad2);
    // K4: layer-2 softmax-aggregate
    k_attn_agg<1, false><<<(N_NODES + 3) / 4, 256, 0, stream>>>(
        cnt, esrc2, ovfc, ovf, h2, as2, ad2, b2, z2);
    // K5: decode
    k_decode<<<(2 * PE_CNT * 8 + 255) / 256, 256, 0, stream>>>(pos_ei, neg_ei, z2, out);

    (void)in_sizes; (void)n_in; (void)out_size; (void)ws_size;
}